// Round 8
// baseline (997.794 us; speedup 1.0000x reference)
//
#include <hip/hip_runtime.h>

typedef __attribute__((ext_vector_type(8))) short bf16x8;
typedef __attribute__((ext_vector_type(4))) float f32x4;
typedef __attribute__((ext_vector_type(8))) unsigned short u16x8;

#define BAR() __builtin_amdgcn_s_barrier()
#define VMC(n) asm volatile("s_waitcnt vmcnt(" #n ")" ::: "memory")

__device__ inline unsigned short f2bf(float f) {
  unsigned int u = __float_as_uint(f);
  u += 0x7fffu + ((u >> 16) & 1u);
  return (unsigned short)(u >> 16);
}

__device__ inline void gload_lds16(const void* g, void* l) {
  __builtin_amdgcn_global_load_lds(
      (const __attribute__((address_space(1))) void*)g,
      (__attribute__((address_space(3))) void*)l, 16, 0, 0);
}

// ---- weight -> fragment-tiled B: Bft[k/32][n/16][lane][8], lane=(n&15)|(((k>>3)&3)<<4)
__global__ void wtrans_ft(const float* __restrict__ W, unsigned short* __restrict__ Bft,
                          int K, int N) {
  int idx = blockIdx.x * 256 + threadIdx.x;
  if (idx >= N * (K >> 3)) return;
  int n = idx % N, k8 = idx / N;
  int k0 = k8 << 3;
  u16x8 ov;
  #pragma unroll
  for (int i = 0; i < 8; ++i) ov[i] = f2bf(W[(size_t)(k0 + i) * N + n]);
  size_t dst = ((size_t)(k0 >> 5) * (N >> 4) + (n >> 4)) * 512 +
               (((n & 15) | (((k0 >> 3) & 3) << 4)) << 3);
  *(u16x8*)&Bft[dst] = ov;
}

// ---- LayerNorm (+shift/window gather), f32 -> bf16 in A-FT layout ----------
// A-FT: Aft[k/32][row/16][lane][8], lane=(row&15)|(((col>>3)&3)<<4); row-frags 3600
template <int MODE>
__global__ void ln_k(const float* __restrict__ x, const float* __restrict__ sc,
                     const float* __restrict__ bi, unsigned short* __restrict__ o) {
  int t = blockIdx.x * 4 + (threadIdx.x >> 6);
  int l = threadIdx.x & 63;
  size_t src;
  if (MODE == 0) {
    int b = t / 28800, r = t - b * 28800;
    int win = r / 144, tok = r - win * 144;
    int c1 = win / 100, rem = win - c1 * 100;
    int h1 = rem / 10, w1 = rem - h1 * 10;
    int tc = tok / 72, tr = tok - tc * 72;
    int th = tr / 12, tw = tr - th * 12;
    int cs = c1 * 2 + tc, hs = h1 * 6 + th, wsp = w1 * 12 + tw;
    int co = (cs + 1) & 3;
    int ho = hs + 3; if (ho >= 60) ho -= 60;
    int wo = wsp + 6; if (wo >= 120) wo -= 120;
    src = ((size_t)b * 28800 + (co * 60 + ho) * 120 + wo) * 512;
  } else {
    src = (size_t)t * 512;
  }
  const float4* xr = (const float4*)(x + src);
  float4 v0 = xr[l * 2], v1 = xr[l * 2 + 1];
  float s = v0.x + v0.y + v0.z + v0.w + v1.x + v1.y + v1.z + v1.w;
  float s2 = v0.x * v0.x + v0.y * v0.y + v0.z * v0.z + v0.w * v0.w +
             v1.x * v1.x + v1.y * v1.y + v1.z * v1.z + v1.w * v1.w;
  #pragma unroll
  for (int o2 = 32; o2; o2 >>= 1) {
    s += __shfl_xor(s, o2);
    s2 += __shfl_xor(s2, o2);
  }
  float mean = s * (1.0f / 512.0f);
  float var = s2 * (1.0f / 512.0f) - mean * mean;
  float inv = rsqrtf(var + 1e-6f);
  const float4* scp = (const float4*)sc;
  const float4* bip = (const float4*)bi;
  float4 sa = scp[l * 2], sb = scp[l * 2 + 1];
  float4 ba = bip[l * 2], bb = bip[l * 2 + 1];
  u16x8 ov;
  ov[0] = f2bf((v0.x - mean) * inv * sa.x + ba.x);
  ov[1] = f2bf((v0.y - mean) * inv * sa.y + ba.y);
  ov[2] = f2bf((v0.z - mean) * inv * sa.z + ba.z);
  ov[3] = f2bf((v0.w - mean) * inv * sa.w + ba.w);
  ov[4] = f2bf((v1.x - mean) * inv * sb.x + bb.x);
  ov[5] = f2bf((v1.y - mean) * inv * sb.y + bb.y);
  ov[6] = f2bf((v1.z - mean) * inv * sb.z + bb.z);
  ov[7] = f2bf((v1.w - mean) * inv * sb.w + bb.w);
  // FT dest: ki = l>>2, row-frag = t>>4, lane-slot = (t&15)|((l&3)<<4)
  size_t dst = ((size_t)(l >> 2) * 3600 + (t >> 4)) * 512 +
               (((t & 15) | ((l & 3) << 4)) << 3);
  *(u16x8*)&o[dst] = ov;
}

// ---- barrier-free FT GEMM: A from global FT (reg dbuf), B via LDS FT -------
// 256 threads / 4 waves; wave tile 128x64 (8mi x 4nf); block tile 512x64.
// LDS: one 512-K segment of B = 16 chunks x 4 nf x 1KB = 64 KiB (2 blocks/CU).
// K-loop: NO barriers; A chunk t+2 prefetched into regs (WAR-ordered after
// MFMA consumption -> ~2-chunk lead, compiler inserts counted vmcnt);
// B read per chunk from LDS (FT order = bank-uniform, conflict-free).
template <int EPI>
__launch_bounds__(256, 2)
__global__ void gemmF(const unsigned short* __restrict__ Aft,
                      const unsigned short* __restrict__ Bft,
                      const float* __restrict__ bias, void* __restrict__ outp,
                      const float* __restrict__ res, int Mreal, int N, int K) {
  __shared__ __attribute__((aligned(16))) unsigned short ldsB[32768];
  const int tid = threadIdx.x;
  const int w = tid >> 6, l = tid & 63;
  const int lane15 = l & 15;
  const int nt = N >> 6;
  // bijective XCD-aware swizzle (m204); consecutive wgid share bm (A L2 reuse)
  const int nwg = gridDim.x;
  const int q = nwg >> 3, r = nwg & 7;
  const int xcd = blockIdx.x & 7, idx8 = blockIdx.x >> 3;
  const int wgid = (xcd < r ? xcd * (q + 1) : r * (q + 1) + (xcd - r) * q) + idx8;
  const int bm = wgid / nt, bn = wgid - bm * nt;
  const int KC = K >> 5;                  // K chunks of 32
  const int NSEG = K >> 9;                // 512-K segments
  const size_t aStep = (size_t)(Mreal >> 4) * 512;  // elems per chunk step

  int rb = bm * 512 + w * 128;
  const bool wactive = rb < Mreal;
  if (!wactive) rb = Mreal - 128;

  const unsigned short* pW = Aft + (size_t)(rb >> 4) * 512 + (size_t)l * 8;

  auto STAGE_SEG = [&](int s) {
    #pragma unroll
    for (int rr = 0; rr < 16; ++rr) {
      size_t srcb = ((size_t)(s * 16 + rr) * (N >> 4) + bn * 4) * 512 + tid * 8;
      gload_lds16(Bft + srcb, &ldsB[rr * 2048 + w * 512]);
    }
  };

  f32x4 acc[8][4] = {};
  bf16x8 a0[8], a1[8];

  // prologue: stage B seg 0; prefetch A chunks 0,1
  STAGE_SEG(0);
  #pragma unroll
  for (int mi = 0; mi < 8; ++mi) a0[mi] = *(const bf16x8*)(pW + mi * 512);
  #pragma unroll
  for (int mi = 0; mi < 8; ++mi) a1[mi] = *(const bf16x8*)(pW + aStep + mi * 512);
  const unsigned short* pPre = pW + 2 * aStep;
  VMC(0);
  BAR();

  for (int s = 0; s < NSEG; ++s) {
    if (s) {
      BAR();             // all waves done reading previous segment
      STAGE_SEG(s);
      VMC(0);
      BAR();
    }
    const int cbase = s * 16;
    #pragma unroll
    for (int k2 = 0; k2 < 8; ++k2) {
      {  // even chunk: consume a0
        const int kl = 2 * k2;
        bf16x8 b0 = *(const bf16x8*)&ldsB[kl * 2048 + 0 * 512 + l * 8];
        bf16x8 b1 = *(const bf16x8*)&ldsB[kl * 2048 + 1 * 512 + l * 8];
        bf16x8 b2 = *(const bf16x8*)&ldsB[kl * 2048 + 2 * 512 + l * 8];
        bf16x8 b3 = *(const bf16x8*)&ldsB[kl * 2048 + 3 * 512 + l * 8];
        #pragma unroll
        for (int mi = 0; mi < 8; ++mi) {
          acc[mi][0] = __builtin_amdgcn_mfma_f32_16x16x32_bf16(a0[mi], b0, acc[mi][0], 0, 0, 0);
          acc[mi][1] = __builtin_amdgcn_mfma_f32_16x16x32_bf16(a0[mi], b1, acc[mi][1], 0, 0, 0);
          acc[mi][2] = __builtin_amdgcn_mfma_f32_16x16x32_bf16(a0[mi], b2, acc[mi][2], 0, 0, 0);
          acc[mi][3] = __builtin_amdgcn_mfma_f32_16x16x32_bf16(a0[mi], b3, acc[mi][3], 0, 0, 0);
        }
        if (cbase + kl + 2 < KC) {
          #pragma unroll
          for (int mi = 0; mi < 8; ++mi) a0[mi] = *(const bf16x8*)(pPre + mi * 512);
          pPre += aStep;
        }
      }
      {  // odd chunk: consume a1
        const int kl = 2 * k2 + 1;
        bf16x8 b0 = *(const bf16x8*)&ldsB[kl * 2048 + 0 * 512 + l * 8];
        bf16x8 b1 = *(const bf16x8*)&ldsB[kl * 2048 + 1 * 512 + l * 8];
        bf16x8 b2 = *(const bf16x8*)&ldsB[kl * 2048 + 2 * 512 + l * 8];
        bf16x8 b3 = *(const bf16x8*)&ldsB[kl * 2048 + 3 * 512 + l * 8];
        #pragma unroll
        for (int mi = 0; mi < 8; ++mi) {
          acc[mi][0] = __builtin_amdgcn_mfma_f32_16x16x32_bf16(a1[mi], b0, acc[mi][0], 0, 0, 0);
          acc[mi][1] = __builtin_amdgcn_mfma_f32_16x16x32_bf16(a1[mi], b1, acc[mi][1], 0, 0, 0);
          acc[mi][2] = __builtin_amdgcn_mfma_f32_16x16x32_bf16(a1[mi], b2, acc[mi][2], 0, 0, 0);
          acc[mi][3] = __builtin_amdgcn_mfma_f32_16x16x32_bf16(a1[mi], b3, acc[mi][3], 0, 0, 0);
        }
        if (cbase + kl + 2 < KC) {
          #pragma unroll
          for (int mi = 0; mi < 8; ++mi) a1[mi] = *(const bf16x8*)(pPre + mi * 512);
          pPre += aStep;
        }
      }
    }
  }

  if (!wactive) return;
  // ---------------- epilogue ----------------
  float* outf = (float*)outp;
  unsigned short* outh = (unsigned short*)outp;
  #pragma unroll
  for (int mi = 0; mi < 8; ++mi) {
    #pragma unroll
    for (int j = 0; j < 4; ++j) {
      int grow = rb + mi * 16 + ((l >> 4) << 2) + j;
      int win = 0, tok = 0;
      size_t rowbase = 0;
      if constexpr (EPI == 0) {
        win = grow / 144;
        tok = grow - win * 144;
      } else if constexpr (EPI == 1) {
        win = grow / 144;
        tok = grow - win * 144;
        int b = win / 200, wl = win - b * 200;
        int c1 = wl / 100, rem = wl - c1 * 100;
        int h1 = rem / 10, w1 = rem - h1 * 10;
        int tc = tok / 72, tr = tok - tc * 72;
        int th = tr / 12, tw = tr - th * 12;
        int cs = c1 * 2 + tc, hs = h1 * 6 + th, wsp = w1 * 12 + tw;
        int co = (cs + 1) & 3;
        int ho = hs + 3; if (ho >= 60) ho -= 60;
        int wo = wsp + 6; if (wo >= 120) wo -= 120;
        rowbase = ((size_t)b * 28800 + (co * 60 + ho) * 120 + wo) * 512;
      }
      #pragma unroll
      for (int nf = 0; nf < 4; ++nf) {
        int gcol = bn * 64 + nf * 16 + lane15;
        float val = acc[mi][nf][j] + bias[gcol];
        if constexpr (EPI == 0) {
          int which = gcol >> 9, hd = (gcol >> 6) & 7, dh = gcol & 63;
          outh[(((size_t)(win * 3 + which) * 8 + hd) * 144 + tok) * 64 + dh] = f2bf(val);
        } else if constexpr (EPI == 1) {
          size_t oi = rowbase + gcol;
          outf[oi] = res[oi] + val;
        } else if constexpr (EPI == 2) {
          float u = 0.7978845608f * (val + 0.044715f * val * val * val);
          float g = val / (1.0f + __expf(-2.0f * u));
          // mid in A-FT layout (3600 row-frags, 2048 cols)
          size_t dst = ((size_t)(gcol >> 5) * 3600 + (grow >> 4)) * 512 +
                       (((grow & 15) | (((gcol >> 3) & 3) << 4)) << 3) + (gcol & 7);
          outh[dst] = f2bf(g);
        } else {
          size_t oi = (size_t)grow * N + gcol;
          outf[oi] += val;
        }
      }
    }
  }
}

// ---------------- attention: one block per (window, head) -------------------
__launch_bounds__(576)
__global__ void attn_k(const unsigned short* __restrict__ qkv,
                       unsigned short* __restrict__ owin) {
  __shared__ __attribute__((aligned(16))) unsigned short Ks[144 * 72];
  __shared__ __attribute__((aligned(16))) unsigned short Vt[64 * 168];
  __shared__ __attribute__((aligned(16))) unsigned short Ps[144 * 168];
  __shared__ unsigned char gid[144];
  int bid = blockIdx.x;
  int win = bid >> 3, head = bid & 7;
  const unsigned short* qb = qkv + ((size_t)(win * 3 + 0) * 8 + head) * (144 * 64);
  const unsigned short* kb = qkv + ((size_t)(win * 3 + 1) * 8 + head) * (144 * 64);
  const unsigned short* vb = qkv + ((size_t)(win * 3 + 2) * 8 + head) * (144 * 64);
  int tid = threadIdx.x;
  {
    int row = tid >> 2, c0 = (tid & 3) << 4;
    u16x8 ka = *(const u16x8*)(kb + row * 64 + c0);
    u16x8 kc = *(const u16x8*)(kb + row * 64 + c0 + 8);
    *(u16x8*)&Ks[row * 72 + c0] = ka;
    *(u16x8*)&Ks[row * 72 + c0 + 8] = kc;
    u16x8 va = *(const u16x8*)(vb + row * 64 + c0);
    u16x8 vc = *(const u16x8*)(vb + row * 64 + c0 + 8);
    #pragma unroll
    for (int j = 0; j < 8; ++j) Vt[(c0 + j) * 168 + row] = va[j];
    #pragma unroll
    for (int j = 0; j < 8; ++j) Vt[(c0 + 8 + j) * 168 + row] = vc[j];
  }
  for (int i = tid; i < 64 * 24; i += 576) {
    int d = i / 24, m = i - d * 24;
    Vt[d * 168 + 144 + m] = 0;
  }
  for (int i = tid; i < 144 * 24; i += 576) {
    int r = i / 24, c = i - r * 24;
    Ps[r * 168 + 144 + c] = 0;
  }
  if (tid < 144) {
    int wl = win % 200;
    int c1 = wl / 100, rem = wl - c1 * 100;
    int h1 = rem / 10, w1 = rem - h1 * 10;
    int tc = tid / 72, tr = tid - tc * 72;
    int th = tr / 12, tw = tr - th * 12;
    int cs = c1 * 2 + tc, hs = h1 * 6 + th, wsp = w1 * 12 + tw;
    int rc = cs < 2 ? 0 : (cs < 3 ? 1 : 2);
    int rh = hs < 54 ? 0 : (hs < 57 ? 1 : 2);
    int rw = wsp < 108 ? 0 : (wsp < 114 ? 1 : 2);
    if (rw == 1) rw = 2;
    gid[tid] = (unsigned char)(rc * 9 + rh * 3 + rw);
  }
  __syncthreads();
  int wv = tid >> 6, l = tid & 63;
  int lane15 = l & 15, lk = (l >> 4) << 3;
  bf16x8 aq0 = *(const bf16x8*)(qb + (wv * 16 + lane15) * 64 + lk);
  bf16x8 aq1 = *(const bf16x8*)(qb + (wv * 16 + lane15) * 64 + 32 + lk);
  f32x4 sf[9];
  #pragma unroll
  for (int ct = 0; ct < 9; ++ct) {
    f32x4 z = {};
    bf16x8 b0 = *(const bf16x8*)&Ks[(ct * 16 + lane15) * 72 + lk];
    bf16x8 b1 = *(const bf16x8*)&Ks[(ct * 16 + lane15) * 72 + 32 + lk];
    z = __builtin_amdgcn_mfma_f32_16x16x32_bf16(aq0, b0, z, 0, 0, 0);
    z = __builtin_amdgcn_mfma_f32_16x16x32_bf16(aq1, b1, z, 0, 0, 0);
    sf[ct] = z;
  }
  int gi[4];
  #pragma unroll
  for (int j = 0; j < 4; ++j) gi[j] = gid[wv * 16 + ((l >> 4) << 2) + j];
  float mx[4] = {-1e30f, -1e30f, -1e30f, -1e30f};
  #pragma unroll
  for (int ct = 0; ct < 9; ++ct) {
    int gj = gid[ct * 16 + lane15];
    #pragma unroll
    for (int j = 0; j < 4; ++j) {
      float s = sf[ct][j] * 0.125f;
      if (gj != gi[j]) s = -1e30f;
      sf[ct][j] = s;
      mx[j] = fmaxf(mx[j], s);
    }
  }
  #pragma unroll
  for (int o2 = 8; o2; o2 >>= 1)
    #pragma unroll
    for (int j = 0; j < 4; ++j) mx[j] = fmaxf(mx[j], __shfl_xor(mx[j], o2));
  float sm[4] = {0.f, 0.f, 0.f, 0.f};
  #pragma unroll
  for (int ct = 0; ct < 9; ++ct)
    #pragma unroll
    for (int j = 0; j < 4; ++j) {
      float e = __expf(sf[ct][j] - mx[j]);
      sf[ct][j] = e;
      sm[j] += e;
    }
  #pragma unroll
  for (int o2 = 8; o2; o2 >>= 1)
    #pragma unroll
    for (int j = 0; j < 4; ++j) sm[j] += __shfl_xor(sm[j], o2);
  float rs[4];
  #pragma unroll
  for (int j = 0; j < 4; ++j) rs[j] = 1.0f / sm[j];
  #pragma unroll
  for (int ct = 0; ct < 9; ++ct)
    #pragma unroll
    for (int j = 0; j < 4; ++j)
      Ps[(wv * 16 + ((l >> 4) << 2) + j) * 168 + ct * 16 + lane15] =
          f2bf(sf[ct][j] * rs[j]);
  __syncthreads();
  f32x4 of[4] = {};
  #pragma unroll
  for (int ks = 0; ks < 5; ++ks) {
    bf16x8 ap = *(const bf16x8*)&Ps[(wv * 16 + lane15) * 168 + ks * 32 + lk];
    #pragma unroll
    for (int nt = 0; nt < 4; ++nt) {
      bf16x8 bv = *(const bf16x8*)&Vt[(nt * 16 + lane15) * 168 + ks * 32 + lk];
      of[nt] = __builtin_amdgcn_mfma_f32_16x16x32_bf16(ap, bv, of[nt], 0, 0, 0);
    }
  }
  // write owin in A-FT layout (3600 row-frags, 512 cols)
  #pragma unroll
  for (int nt = 0; nt < 4; ++nt)
    #pragma unroll
    for (int j = 0; j < 4; ++j) {
      int row = win * 144 + wv * 16 + ((l >> 4) << 2) + j;
      int col = head * 64 + nt * 16 + lane15;
      size_t dst = ((size_t)(col >> 5) * 3600 + (row >> 4)) * 512 +
                   (((row & 15) | (((col >> 3) & 3) << 4)) << 3) + (col & 7);
      owin[dst] = f2bf(of[nt][j]);
    }
}

extern "C" void kernel_launch(void* const* d_in, const int* in_sizes, int n_in,
                              void* d_out, int out_size, void* d_ws, size_t ws_size,
                              hipStream_t stream) {
  const float* x = (const float*)d_in[0];
  const float* qkv_w = (const float*)d_in[1];
  const float* qkv_b = (const float*)d_in[2];
  const float* proj_w = (const float*)d_in[3];
  const float* proj_b = (const float*)d_in[4];
  const float* n1s = (const float*)d_in[5];
  const float* n1b = (const float*)d_in[6];
  const float* n2s = (const float*)d_in[7];
  const float* n2b = (const float*)d_in[8];
  const float* w1 = (const float*)d_in[9];
  const float* b1 = (const float*)d_in[10];
  const float* w2 = (const float*)d_in[11];
  const float* b2 = (const float*)d_in[12];
  float* out = (float*)d_out;
  char* ws = (char*)d_ws;

  unsigned short* WqT = (unsigned short*)(ws);               // FT-B 512x1536
  unsigned short* WpT = (unsigned short*)(ws + 1572864);     // FT-B 512x512
  unsigned short* W1T = (unsigned short*)(ws + 2097152);     // FT-B 512x2048
  unsigned short* W2T = (unsigned short*)(ws + 4194304);     // FT-B 2048x512
  unsigned short* hwin = (unsigned short*)(ws + 6291456);    // FT-A 57600x512
  unsigned short* qkvb = (unsigned short*)(ws + 65273856);   // 57600x1536 (attn fmt)
  unsigned short* owin = (unsigned short*)(ws + 242221056);  // FT-A 57600x512
  unsigned short* mid = qkvb;  // FT-A 57600x2048 (aliases qkvb+owin exactly)

  wtrans_ft<<<(1536 * 64 + 255) / 256, 256, 0, stream>>>(qkv_w, WqT, 512, 1536);
  wtrans_ft<<<(512 * 64 + 255) / 256, 256, 0, stream>>>(proj_w, WpT, 512, 512);
  wtrans_ft<<<(2048 * 64 + 255) / 256, 256, 0, stream>>>(w1, W1T, 512, 2048);
  wtrans_ft<<<(512 * 256 + 255) / 256, 256, 0, stream>>>(w2, W2T, 2048, 512);
  ln_k<0><<<14400, 256, 0, stream>>>(x, n1s, n1b, hwin);
  gemmF<0><<<113 * 24, 256, 0, stream>>>(hwin, WqT, qkv_b, qkvb, nullptr, 57600, 1536, 512);
  attn_k<<<3200, 576, 0, stream>>>(qkvb, owin);
  gemmF<1><<<113 * 8, 256, 0, stream>>>(owin, WpT, proj_b, out, x, 57600, 512, 512);
  ln_k<1><<<14400, 256, 0, stream>>>(out, n2s, n2b, hwin);
  gemmF<2><<<113 * 32, 256, 0, stream>>>(hwin, W1T, b1, mid, nullptr, 57600, 2048, 512);
  gemmF<3><<<113 * 8, 256, 0, stream>>>(mid, W2T, b2, out, nullptr, 57600, 512, 2048);
}